// Round 5
// baseline (278.221 us; speedup 1.0000x reference)
//
#include <hip/hip_runtime.h>
#include <hip/hip_bf16.h>
#include <stdint.h>

// Problem constants (AttentionLayer: B=2, L=2048, H=1024, NH=16, HD=64)
#define H_DIM  1024
#define NHEADS 16
#define HDIM   64
#define BATCH  2
#define SEQ    2048
#define MROWS  (BATCH * SEQ)   // 4096
#define QKV_N  (3 * H_DIM)     // 3072
#define LSTR   72              // padded LDS row stride for transpose kernel
#define QSCALE 0.18033688f     // 0.125 * log2(e)

typedef __attribute__((ext_vector_type(8))) __bf16 bf16x8;
typedef __attribute__((ext_vector_type(4))) float  floatx4;

__device__ __forceinline__ unsigned short f2bf(float f) {
    uint32_t u = __float_as_uint(f);
    u += 0x7fffu + ((u >> 16) & 1u);
    return (unsigned short)(u >> 16);
}
__device__ __forceinline__ unsigned short f2bf_fast(float f) {   // round-half-up (2 ops)
    return (unsigned short)((__float_as_uint(f) + 0x8000u) >> 16);
}

// async global->LDS, 16B per lane; lptr must be wave-uniform [m97 pattern]
__device__ __forceinline__ void async_ld16(const void* g, void* l) {
    __builtin_amdgcn_global_load_lds(
        (const __attribute__((address_space(1))) void*)g,
        (__attribute__((address_space(3))) void*)l, 16, 0, 0);
}

// ---------------------------------------------------------------- cvt fp32 -> bf16
__global__ __launch_bounds__(256) void cvt_f32_bf16(const float4* __restrict__ in,
                                                    ushort4* __restrict__ out, int n4) {
    int i = blockIdx.x * 256 + threadIdx.x;
    if (i < n4) {
        float4 v = in[i];
        ushort4 o;
        o.x = f2bf(v.x); o.y = f2bf(v.y); o.z = f2bf(v.z); o.w = f2bf(v.w);
        out[i] = o;
    }
}

// ---------------------------------------------------------------- GEMM (B^T form)
// C[m][n] = sum_k A[m][k]*B[n][k] + bias[n].  A:[M,K] bf16, B:[N,K] bf16.
// m97-style global_load_lds staging. scale_q: cols < H_DIM get *QSCALE (QKV gemm).
// All stores coalesced (no scatter).
__global__ __launch_bounds__(256) void gemm_bt(const unsigned short* __restrict__ A,
                                               const unsigned short* __restrict__ B,
                                               const float* __restrict__ bias,
                                               unsigned short* __restrict__ Cb,
                                               float* __restrict__ Cf,
                                               int scale_q, int ldc, int Kdim) {
    __shared__ __align__(16) unsigned short As[128 * 32];
    __shared__ __align__(16) unsigned short Bs[128 * 32];
    const int tid  = threadIdx.x;
    const int lane = tid & 63;
    const int wave = tid >> 6;
    const int waveM = (wave >> 1) * 64;
    const int waveN = (wave & 1) * 64;
    const int bm = blockIdx.y, bn = blockIdx.x;

    floatx4 acc[4][4];
    #pragma unroll
    for (int i = 0; i < 4; ++i)
        #pragma unroll
        for (int j = 0; j < 4; ++j) {
            floatx4 z = {0.f, 0.f, 0.f, 0.f};
            acc[i][j] = z;
        }

    const int c0 = tid, c1 = tid + 256;
    const int r0 = c0 >> 2, kc0 = (c0 & 3) * 8;
    const int r1 = c1 >> 2, kc1 = (c1 & 3) * 8;
    char* asb0 = (char*)As + wave * 1024;
    char* asb1 = (char*)As + 4096 + wave * 1024;
    char* bsb0 = (char*)Bs + wave * 1024;
    char* bsb1 = (char*)Bs + 4096 + wave * 1024;

    const int lr = lane & 15;
    const int lk = (lane >> 4) * 8;

    for (int k0 = 0; k0 < Kdim; k0 += 32) {
        async_ld16(&A[(size_t)(bm * 128 + r0) * Kdim + k0 + kc0], asb0);
        async_ld16(&A[(size_t)(bm * 128 + r1) * Kdim + k0 + kc1], asb1);
        async_ld16(&B[(size_t)(bn * 128 + r0) * Kdim + k0 + kc0], bsb0);
        async_ld16(&B[(size_t)(bn * 128 + r1) * Kdim + k0 + kc1], bsb1);
        __syncthreads();

        bf16x8 af[4], bfr[4];
        #pragma unroll
        for (int i = 0; i < 4; ++i)
            af[i] = *(const bf16x8*)&As[(waveM + i * 16 + lr) * 32 + lk];
        #pragma unroll
        for (int j = 0; j < 4; ++j)
            bfr[j] = *(const bf16x8*)&Bs[(waveN + j * 16 + lr) * 32 + lk];

        #pragma unroll
        for (int i = 0; i < 4; ++i)
            #pragma unroll
            for (int j = 0; j < 4; ++j)
                acc[i][j] = __builtin_amdgcn_mfma_f32_16x16x32_bf16(af[i], bfr[j], acc[i][j], 0, 0, 0);
        __syncthreads();
    }

    // C/D layout: col=lane&15, row=(lane>>4)*4+reg  [m89/m91]
    const int crow0 = bm * 128 + waveM + (lane >> 4) * 4;
    const int ccol0 = bn * 128 + waveN + (lane & 15);
    #pragma unroll
    for (int i = 0; i < 4; ++i)
        #pragma unroll
        for (int j = 0; j < 4; ++j) {
            int col = ccol0 + j * 16;
            float bv = bias[col];
            float sc = (scale_q && col < H_DIM) ? QSCALE : 1.f;
            #pragma unroll
            for (int r = 0; r < 4; ++r) {
                int row = crow0 + i * 16 + r;
                float v = (acc[i][j][r] + bv) * sc;
                if (Cb) Cb[(size_t)row * ldc + col] = f2bf(v);
                else    Cf[(size_t)row * ldc + col] = v;
            }
        }
}

// ---------------------------------------------------------------- V transpose
// vt[bh][d][kv] (bf16) from qkv's V columns. One 64x64 tile per block. Coalesced.
__global__ __launch_bounds__(256) void vt_transpose(const unsigned short* __restrict__ qkv,
                                                    unsigned short* __restrict__ vt) {
    __shared__ __align__(16) unsigned short Vs[64 * LSTR];
    const int bh = blockIdx.y;
    const int b = bh >> 4, h = bh & 15;
    const int kv0 = blockIdx.x * 64;
    const int tid = threadIdx.x;

    #pragma unroll
    for (int c = tid; c < 512; c += 256) {
        const int row = c >> 3, off = (c & 7) * 8;
        *(int4*)&Vs[row * LSTR + off] =
            *(const int4*)&qkv[(size_t)(b * SEQ + kv0 + row) * QKV_N + 2 * H_DIM + h * HDIM + off];
    }
    __syncthreads();
    #pragma unroll
    for (int c = tid; c < 512; c += 256) {
        const int d = c >> 3, koff = (c & 7) * 8;
        unsigned short tmp[8];
        #pragma unroll
        for (int i = 0; i < 8; ++i) tmp[i] = Vs[(koff + i) * LSTR + d];
        *(int4*)&vt[(size_t)bh * HDIM * SEQ + (size_t)d * SEQ + kv0 + koff] = *(int4*)tmp;
    }
}

// ---------------------------------------------------------------- MFMA flash attention
// Grid 512, block 512 thr = 8 waves: ih=wave>>1 picks 32 Q rows (of 128/block),
// j=wave&1 picks KV half of the staged 128-kv tile. Register-prefetch pipeline:
// load tile t+1 into VGPRs at top of iter, compute tile t from single LDS buffer,
// barrier, ds_write regs, barrier. No online max (additive partials; j-halves
// combine exactly through LDS at the end). XOR-swizzled unpadded LDS tiles.
__global__ __launch_bounds__(512, 4) void attn_mfma(const unsigned short* __restrict__ qkv,
                                                    const unsigned short* __restrict__ vt,
                                                    unsigned short* __restrict__ ctx) {
    __shared__ __align__(16) unsigned short KV[128 * 64 + 64 * 128];  // Ks | Vts, 32KB
    __shared__ __align__(16) unsigned short Ps[8 * 16 * 64];          // 16KB, per-wave P
    unsigned short* Ks  = KV;
    unsigned short* Vts = KV + 128 * 64;

    const int tid  = threadIdx.x;
    const int lane = tid & 63;
    const int wave = tid >> 6;          // 0..7
    const int ih   = wave >> 1;         // Q strip-pair
    const int j    = wave & 1;          // KV half
    const int id = blockIdx.x;
    const int bh = id & 31;             // XCD swizzle: same bh -> same XCD
    const int qt = id >> 5;             // 0..15
    const int b  = bh >> 4, h = bh & 15;
    const int q0 = qt * 128 + ih * 32;
    const int lq = lane & 15;
    const int g  = lane >> 4;

    unsigned short* Pw = &Ps[wave * 1024];   // 16 rows x 64 kv, swizzled

    // Q fragments (pre-scaled by QSCALE in gemm1): A-layout m=lq, k=g*8+..
    bf16x8 qf[2][2];
    #pragma unroll
    for (int s = 0; s < 2; ++s)
        #pragma unroll
        for (int kk = 0; kk < 2; ++kk)
            qf[s][kk] = *(const bf16x8*)&qkv[(size_t)(b * SEQ + q0 + s * 16 + lq) * QKV_N
                                             + h * HDIM + kk * 32 + g * 8];

    floatx4 acc_o[2][4];
    #pragma unroll
    for (int s = 0; s < 2; ++s)
        #pragma unroll
        for (int dt = 0; dt < 4; ++dt) {
            floatx4 z = {0.f, 0.f, 0.f, 0.f};
            acc_o[s][dt] = z;
        }
    float l_run[2] = {0.f, 0.f};

    const size_t kbase  = (size_t)b * SEQ * QKV_N + H_DIM + (size_t)h * HDIM;
    const size_t vtbase = (size_t)bh * HDIM * SEQ;

    // staging coords: 2 K chunks + 2 Vt chunks per thread (2048 chunks / 512 thr)
    int kR[2], kO[2], kS[2], dR[2], vO[2], vS[2];
    #pragma unroll
    for (int i = 0; i < 2; ++i) {
        int n = tid + 512 * i;            // 0..1023
        kR[i] = n >> 3; int kc = n & 7;
        kO[i] = kc * 8;
        kS[i] = kR[i] * 64 + (kc ^ (kR[i] & 7)) * 8;
        dR[i] = n >> 4; int vc = n & 15;
        vO[i] = vc * 8;
        vS[i] = dR[i] * 128 + ((vc & 8) | ((vc & 7) ^ (dR[i] & 7))) * 8;
    }

    // prologue: tile 0
    uint4 rk[2], rv[2];
    #pragma unroll
    for (int i = 0; i < 2; ++i) {
        rk[i] = *(const uint4*)&qkv[kbase + (size_t)kR[i] * QKV_N + kO[i]];
        rv[i] = *(const uint4*)&vt [vtbase + (size_t)dR[i] * SEQ + vO[i]];
    }
    #pragma unroll
    for (int i = 0; i < 2; ++i) {
        *(uint4*)&Ks [kS[i]] = rk[i];
        *(uint4*)&Vts[vS[i]] = rv[i];
    }
    __syncthreads();

    for (int t = 0; t < 16; ++t) {
        if (t < 15) {                        // prefetch tile t+1 into regs
            const int kvn = (t + 1) * 128;
            #pragma unroll
            for (int i = 0; i < 2; ++i) {
                rk[i] = *(const uint4*)&qkv[kbase + (size_t)(kvn + kR[i]) * QKV_N + kO[i]];
                rv[i] = *(const uint4*)&vt [vtbase + (size_t)dR[i] * SEQ + kvn + vO[i]];
            }
        }

        // K A-frags (m = kv row, k = d) and Vt B-frags (n = d row, k = kv), swizzled
        bf16x8 kf[4][2], vf[4][2];
        #pragma unroll
        for (int jb = 0; jb < 4; ++jb) {
            const int krow = j * 64 + jb * 16 + lq;
            #pragma unroll
            for (int kk = 0; kk < 2; ++kk)
                kf[jb][kk] = *(const bf16x8*)&Ks[krow * 64 + ((kk * 4 + g) ^ (krow & 7)) * 8];
        }
        #pragma unroll
        for (int dt = 0; dt < 4; ++dt) {
            const int drow = dt * 16 + lq;
            #pragma unroll
            for (int kk = 0; kk < 2; ++kk)
                vf[dt][kk] = *(const bf16x8*)&Vts[drow * 128 + (j * 8 + ((kk * 4 + g) ^ (drow & 7))) * 8];
        }

        #pragma unroll
        for (int s = 0; s < 2; ++s) {
            // S^T: lane holds S[q=lq][kv = jb*16 + g*4 + r]
            floatx4 sa[4];
            #pragma unroll
            for (int jb = 0; jb < 4; ++jb) {
                floatx4 z = {0.f, 0.f, 0.f, 0.f};
                sa[jb] = z;
            }
            #pragma unroll
            for (int jb = 0; jb < 4; ++jb)
                #pragma unroll
                for (int kk = 0; kk < 2; ++kk)
                    sa[jb] = __builtin_amdgcn_mfma_f32_16x16x32_bf16(kf[jb][kk], qf[s][kk], sa[jb], 0, 0, 0);

            float ps = 0.f;
            #pragma unroll
            for (int jb = 0; jb < 4; ++jb) {
                float p0 = exp2f(sa[jb][0]), p1 = exp2f(sa[jb][1]);
                float p2 = exp2f(sa[jb][2]), p3 = exp2f(sa[jb][3]);
                ps += (p0 + p1) + (p2 + p3);
                ushort4 pk;
                pk.x = f2bf_fast(p0); pk.y = f2bf_fast(p1);
                pk.z = f2bf_fast(p2); pk.w = f2bf_fast(p3);
                // kv = jb*16+g*4+r -> chunk jb*2+(g>>1), offset (g&1)*4; XOR-swizzle by lq
                *(ushort4*)&Pw[lq * 64 + ((jb * 2 + (g >> 1)) ^ (lq & 7)) * 8 + (g & 1) * 4] = pk;
            }
            ps += __shfl_xor(ps, 16);
            ps += __shfl_xor(ps, 32);
            l_run[s] += ps;

            bf16x8 pf[2];
            #pragma unroll
            for (int kk = 0; kk < 2; ++kk)
                pf[kk] = *(const bf16x8*)&Pw[lq * 64 + ((kk * 4 + g) ^ (lq & 7)) * 8];
            #pragma unroll
            for (int dt = 0; dt < 4; ++dt)
                #pragma unroll
                for (int kk = 0; kk < 2; ++kk)
                    acc_o[s][dt] = __builtin_amdgcn_mfma_f32_16x16x32_bf16(pf[kk], vf[dt][kk], acc_o[s][dt], 0, 0, 0);
        }
        __syncthreads();                     // all waves done reading LDS tile t
        if (t < 15) {
            #pragma unroll
            for (int i = 0; i < 2; ++i) {    // commit prefetched tile t+1
                *(uint4*)&Ks [kS[i]] = rk[i];
                *(uint4*)&Vts[vS[i]] = rv[i];
            }
            __syncthreads();
        }
    }

    // combine the two KV halves (fp32 via LDS; Ks/Vts and Ps are dead)
    float* Osh = (float*)KV;                 // 8192 floats
    float* Lsh = (float*)Ps;                 // 128 floats
    if (j == 1) {
        #pragma unroll
        for (int s = 0; s < 2; ++s) {
            #pragma unroll
            for (int dt = 0; dt < 4; ++dt)
                *(floatx4*)&Osh[(((ih * 2 + s) * 4 + dt) << 8) + lane * 4] = acc_o[s][dt];
            if (g == 0) Lsh[(ih * 2 + s) * 16 + lq] = l_run[s];
        }
    }
    __syncthreads();
    if (j == 0) {
        #pragma unroll
        for (int s = 0; s < 2; ++s) {
            float lt = l_run[s] + Lsh[(ih * 2 + s) * 16 + lq];
            float linv[4];
            #pragma unroll
            for (int r = 0; r < 4; ++r)
                linv[r] = 1.f / __shfl(lt, g * 4 + r);   // lane g*4+r holds row g*4+r
            #pragma unroll
            for (int dt = 0; dt < 4; ++dt) {
                floatx4 oo = *(const floatx4*)&Osh[(((ih * 2 + s) * 4 + dt) << 8) + lane * 4];
                #pragma unroll
                for (int r = 0; r < 4; ++r) {
                    int row = q0 + s * 16 + g * 4 + r;
                    ctx[(size_t)(b * SEQ + row) * H_DIM + h * HDIM + dt * 16 + lq]
                        = f2bf((acc_o[s][dt][r] + oo[r]) * linv[r]);
                }
            }
        }
    }
}

// ---------------------------------------------------------------- launcher
extern "C" void kernel_launch(void* const* d_in, const int* in_sizes, int n_in,
                              void* d_out, int out_size, void* d_ws, size_t ws_size,
                              hipStream_t stream) {
    const float* x     = (const float*)d_in[0];
    const float* w_qkv = (const float*)d_in[1];
    const float* b_qkv = (const float*)d_in[2];
    const float* w_out = (const float*)d_in[3];
    const float* b_out = (const float*)d_in[4];
    float* out = (float*)d_out;

    // workspace (bf16 elements): 4M+3M+1M+12M+4M = 24M shorts = 48 MB
    unsigned short* xb    = (unsigned short*)d_ws;               // 4096*1024 (reused as Vt)
    unsigned short* wqkvb = xb    + (size_t)MROWS * H_DIM;       // 3072*1024
    unsigned short* woutb = wqkvb + (size_t)QKV_N * H_DIM;       // 1024*1024
    unsigned short* qkvb  = woutb + (size_t)H_DIM * H_DIM;       // 4096*3072 (Q scaled|K|V)
    unsigned short* ctxb  = qkvb  + (size_t)MROWS * QKV_N;       // 4096*1024

    cvt_f32_bf16<<<MROWS * H_DIM / 1024, 256, 0, stream>>>((const float4*)x,     (ushort4*)xb,    MROWS * H_DIM / 4);
    cvt_f32_bf16<<<QKV_N * H_DIM / 1024, 256, 0, stream>>>((const float4*)w_qkv, (ushort4*)wqkvb, QKV_N * H_DIM / 4);
    cvt_f32_bf16<<<H_DIM * H_DIM / 1024, 256, 0, stream>>>((const float4*)w_out, (ushort4*)woutb, H_DIM * H_DIM / 4);

    // qkv = x @ w_qkv^T + b_qkv (Q cols pre-scaled by QSCALE), all coalesced
    gemm_bt<<<dim3(QKV_N / 128, MROWS / 128), 256, 0, stream>>>(xb, wqkvb, b_qkv, qkvb, nullptr, 1, QKV_N, H_DIM);

    // Vt[bh][d][kv] (xb is dead after gemm1; exactly 4M shorts)
    unsigned short* vtb = xb;
    vt_transpose<<<dim3(SEQ / 64, BATCH * NHEADS), 256, 0, stream>>>(qkvb, vtb);

    // flash attention -> ctx bf16 [4096, 1024]
    attn_mfma<<<(SEQ / 128) * BATCH * NHEADS, 512, 0, stream>>>(qkvb, vtb, ctxb);

    // out = ctx @ w_out^T + b_out -> fp32 [4096, 1024]
    gemm_bt<<<dim3(H_DIM / 128, MROWS / 128), 256, 0, stream>>>(ctxb, woutb, b_out, nullptr, out, 0, H_DIM, H_DIM);
}